// Round 1
// baseline (86.815 us; speedup 1.0000x reference)
//
#include <hip/hip_runtime.h>
#include <hip/hip_bf16.h>

// PartiallyExchangeableNetwork on MI355X (gfx950)
// N=256, M=3, T=4096, ORDER=2 -> L=4094 windows, H=128, OUT=10
//
// Heavy path: h1 = relu(xin @ W1 + b1); h2 = relu(h1 @ W2 + b2); colsum over L.
// Layer 3 folded through the sum: sum_l(h2@W3+b3) = (sum_l h2)@W3 + L*b3 (tail kernel).

#define NN 256
#define MM 3
#define TT 4096
#define LL 4094
#define HH 128
#define CHUNKS 8
#define RPC 512          // rows (windows) per chunk
#define STEPS 8
#define SR 64            // rows per step (block tile)

typedef __attribute__((ext_vector_type(8))) short bf16x8;
typedef __attribute__((ext_vector_type(4))) float f32x4;
typedef __attribute__((ext_vector_type(4))) unsigned short u16x4;

__device__ __forceinline__ unsigned short f2bf(float x) {
    union { float f; unsigned u; } v; v.f = x;
    unsigned r = v.u + 0x7fffu + ((v.u >> 16) & 1u);   // RNE to bf16
    return (unsigned short)(r >> 16);
}

// ---------------------------------------------------------------------------
// Kernel A: per (n, chunk-of-512-windows): layers 1+2, masked column sums.
// Wave w owns output channels [32w, 32w+32); all 64 rows of each step.
// ---------------------------------------------------------------------------
__global__ __launch_bounds__(256, 2) void pen_inner(
    const float* __restrict__ x,
    const float* __restrict__ w1, const float* __restrict__ b1,
    const float* __restrict__ w2, const float* __restrict__ b2,
    float* __restrict__ partials)
{
    // x windows staged row-major: xw[r*12 + k] = xin[l0c+r][k], k = i*3+m (stride 12 -> 16B
    // aligned rows, 2-way-max LDS bank aliasing on the b128 reads).
    __shared__ __align__(16) float xw[RPC * 12];
    // h1 tile, bf16 bits, XOR-swizzled halfword index within each 128-wide row.
    __shared__ __align__(16) unsigned short h1s[SR * HH];

    const int tid  = threadIdx.x;
    const int wave = tid >> 6;
    const int lane = tid & 63;
    const int lr   = lane & 15;   // MFMA "lane&15" index (A-row / B-col / D-col)
    const int lq   = lane >> 4;   // 0..3

    const int bx    = blockIdx.x;
    const int n     = bx >> 3;
    const int chunk = bx & 7;
    const int l0c   = chunk * RPC;

    // ---- stage x windows (once per block) ----
    const float* xn = x + n * (MM * TT);
    for (int idx = tid; idx < RPC * 9; idx += 256) {
        int r = idx / 9;
        int k = idx - r * 9;
        int i = k / 3;            // lag
        int m = k - i * 3;        // timeseries
        int t = l0c + r + i;
        xw[r * 12 + k] = (t < TT) ? xn[m * TT + t] : 0.f;   // clamp: masked rows only
    }

    // ---- preload weight fragments (registers; K=9 padded to 32, bias at k=9) ----
    const int fo0 = wave * 2;              // this wave's two 16-wide o-fragments
    bf16x8 w1f[2];                         // A1 = W1^T : [c][k]
    bf16x8 w2f[2][4];                      // A2 = W2^T : [o][i], 4 k-chunks of 32
    float  b2v[2][4];
    #pragma unroll
    for (int f = 0; f < 2; ++f) {
        const int c = (fo0 + f) * 16 + lr;
        bf16x8 a;
        #pragma unroll
        for (int e = 0; e < 8; ++e) {
            int k = lq * 8 + e;
            float v = 0.f;
            if (k < 9)       v = w1[k * HH + c];
            else if (k == 9) v = b1[c];
            a[e] = (short)f2bf(v);
        }
        w1f[f] = a;
        #pragma unroll
        for (int kk = 0; kk < 4; ++kk) {
            bf16x8 wv;
            #pragma unroll
            for (int e = 0; e < 8; ++e) {
                int i = kk * 32 + lq * 8 + e;
                wv[e] = (short)f2bf(w2[i * HH + c]);
            }
            w2f[f][kk] = wv;
        }
        #pragma unroll
        for (int j = 0; j < 4; ++j) b2v[f][j] = b2[(fo0 + f) * 16 + lq * 4 + j];
    }

    float colsum[2][4] = {{0.f,0.f,0.f,0.f},{0.f,0.f,0.f,0.f}};
    const f32x4 zero4 = {0.f, 0.f, 0.f, 0.f};

    for (int s = 0; s < STEPS; ++s) {
        __syncthreads();   // h1s reads of previous step complete (and xw staged, s==0)

        // ---- layer 1: D1[c][r] = W1^T @ xin^T (+bias channel) ----
        f32x4 acc1[2][4];
        #pragma unroll
        for (int rf = 0; rf < 4; ++rf) {
            const int r = s * SR + rf * 16 + lr;     // row within chunk
            bf16x8 bfrag;
            #pragma unroll
            for (int e = 0; e < 8; ++e) bfrag[e] = 0;
            if (lq == 0) {                            // k = 0..7
                f32x4 lo = *(const f32x4*)&xw[r * 12];
                f32x4 hi = *(const f32x4*)&xw[r * 12 + 4];
                #pragma unroll
                for (int e = 0; e < 4; ++e) bfrag[e]     = (short)f2bf(lo[e]);
                #pragma unroll
                for (int e = 0; e < 4; ++e) bfrag[4 + e] = (short)f2bf(hi[e]);
            } else if (lq == 1) {                     // k = 8 (data), k = 9 (bias one)
                bfrag[0] = (short)f2bf(xw[r * 12 + 8]);
                bfrag[1] = (short)0x3F80;             // bf16(1.0)
            }
            #pragma unroll
            for (int f = 0; f < 2; ++f)
                acc1[f][rf] = __builtin_amdgcn_mfma_f32_16x16x32_bf16(
                                  w1f[f], bfrag, zero4, 0, 0, 0);
        }

        // ---- relu + bf16 + swizzled LDS store: h1s[r][c], idx ^= (r&7)<<3 ----
        #pragma unroll
        for (int rf = 0; rf < 4; ++rf) {
            const int r   = rf * 16 + lr;
            const int swz = (r & 7) << 3;
            #pragma unroll
            for (int f = 0; f < 2; ++f) {
                const int cbase = (fo0 + f) * 16 + lq * 4;
                u16x4 pk;
                #pragma unroll
                for (int j = 0; j < 4; ++j)
                    pk[j] = f2bf(fmaxf(acc1[f][rf][j], 0.f));
                *(u16x4*)&h1s[r * HH + (cbase ^ swz)] = pk;
            }
        }
        __syncthreads();

        // ---- layer 2: D2[o][r] = W2^T @ h1^T, accumulate over 4 K-chunks ----
        f32x4 acc2[2][4];
        #pragma unroll
        for (int f = 0; f < 2; ++f)
            #pragma unroll
            for (int rf = 0; rf < 4; ++rf) acc2[f][rf] = zero4;

        #pragma unroll
        for (int rf = 0; rf < 4; ++rf) {
            const int r   = rf * 16 + lr;
            const int swz = (r & 7) << 3;
            bf16x8 hf[4];
            #pragma unroll
            for (int kk = 0; kk < 4; ++kk) {
                const int ibase = kk * 32 + lq * 8;
                hf[kk] = *(const bf16x8*)&h1s[r * HH + (ibase ^ swz)];
            }
            #pragma unroll
            for (int f = 0; f < 2; ++f)
                #pragma unroll
                for (int kk = 0; kk < 4; ++kk)
                    acc2[f][rf] = __builtin_amdgcn_mfma_f32_16x16x32_bf16(
                                      w2f[f][kk], hf[kk], acc2[f][rf], 0, 0, 0);
        }

        // ---- bias + relu + masked column-sum accumulation ----
        #pragma unroll
        for (int rf = 0; rf < 4; ++rf) {
            const bool valid = (l0c + s * SR + rf * 16 + lr) < LL;
            #pragma unroll
            for (int f = 0; f < 2; ++f)
                #pragma unroll
                for (int j = 0; j < 4; ++j) {
                    float v = fmaxf(acc2[f][rf][j] + b2v[f][j], 0.f);
                    if (valid) colsum[f][j] += v;
                }
        }
    }

    // ---- reduce colsum over the 16 r-lanes, write block partial (no atomics) ----
    #pragma unroll
    for (int f = 0; f < 2; ++f)
        #pragma unroll
        for (int j = 0; j < 4; ++j) {
            float v = colsum[f][j];
            #pragma unroll
            for (int msk = 1; msk < 16; msk <<= 1)
                v += __shfl_xor(v, msk, 64);
            if (lr == 0) {
                const int o = (fo0 + f) * 16 + lq * 4 + j;
                partials[(n * CHUNKS + chunk) * HH + o] = v;
            }
        }
}

// ---------------------------------------------------------------------------
// Kernel B: tail in fp32. inner = sum partials; oi = inner@W3 + L*b3;
// io = [x[:, :, :2] flat (6), oi]; g = relu(io@rw1+rb1); out = g@rw2+rb2.
// ---------------------------------------------------------------------------
__global__ __launch_bounds__(128) void pen_outer(
    const float* __restrict__ x,
    const float* __restrict__ w3, const float* __restrict__ b3,
    const float* __restrict__ rw1, const float* __restrict__ rb1,
    const float* __restrict__ rw2, const float* __restrict__ rb2,
    const float* __restrict__ partials,
    float* __restrict__ out)
{
    __shared__ float S[HH];
    __shared__ float IO[136];
    __shared__ float G[HH];
    const int n = blockIdx.x;
    const int c = threadIdx.x;

    float s = 0.f;
    #pragma unroll
    for (int ch = 0; ch < CHUNKS; ++ch)
        s += partials[(n * CHUNKS + ch) * HH + c];
    S[c] = s;
    if (c < 6) IO[c] = x[n * (MM * TT) + (c >> 1) * TT + (c & 1)];
    __syncthreads();

    float oi = (float)LL * b3[c];
    for (int k = 0; k < HH; ++k) oi += S[k] * w3[k * HH + c];
    IO[6 + c] = oi;
    __syncthreads();

    float g = rb1[c];
    for (int k = 0; k < 134; ++k) g += IO[k] * rw1[k * HH + c];
    G[c] = fmaxf(g, 0.f);
    __syncthreads();

    if (c < 10) {
        float o = rb2[c];
        for (int k = 0; k < HH; ++k) o += G[k] * rw2[k * 10 + c];
        out[n * 10 + c] = o;
    }
}

// ---------------------------------------------------------------------------
extern "C" void kernel_launch(void* const* d_in, const int* in_sizes, int n_in,
                              void* d_out, int out_size, void* d_ws, size_t ws_size,
                              hipStream_t stream)
{
    (void)in_sizes; (void)n_in; (void)out_size; (void)ws_size;
    const float* x   = (const float*)d_in[0];
    const float* w1  = (const float*)d_in[1];
    const float* b1  = (const float*)d_in[2];
    const float* w2  = (const float*)d_in[3];
    const float* b2  = (const float*)d_in[4];
    const float* w3  = (const float*)d_in[5];
    const float* b3  = (const float*)d_in[6];
    const float* rw1 = (const float*)d_in[7];
    const float* rb1 = (const float*)d_in[8];
    const float* rw2 = (const float*)d_in[9];
    const float* rb2 = (const float*)d_in[10];

    float* partials = (float*)d_ws;   // NN*CHUNKS*HH floats = 1 MiB of scratch

    pen_inner<<<NN * CHUNKS, 256, 0, stream>>>(x, w1, b1, w2, b2, partials);
    pen_outer<<<NN, 128, 0, stream>>>(x, w3, b3, rw1, rb1, rw2, rb2, partials,
                                      (float*)d_out);
}

// Round 3
// 73.013 us; speedup vs baseline: 1.1890x; 1.1890x over previous
//
#include <hip/hip_runtime.h>
#include <hip/hip_bf16.h>

// PartiallyExchangeableNetwork on MI355X (gfx950)
// N=256, M=3, T=4096, ORDER=2 -> L=4094 windows, H=128, OUT=10
//
// h1 = relu(xin @ W1 + b1); h2 = relu(h1 @ W2 + b2); colsum over L.
// Layer 3 folded through the sum: sum_l(h2@W3+b3) = (sum_l h2)@W3 + L*b3 (tail kernel).

#define NN 256
#define MM 3
#define TT 4096
#define LL 4094
#define HH 128
#define CHUNKS 8
#define RPC 512          // rows (windows) per chunk
#define STEPS 8
#define SR 64            // rows per step (block tile)

typedef __attribute__((ext_vector_type(8))) short bf16x8;
typedef __attribute__((ext_vector_type(4))) float f32x4;
typedef __attribute__((ext_vector_type(4))) unsigned short u16x4;
typedef __attribute__((ext_vector_type(2))) unsigned int u32x2;

__device__ __forceinline__ unsigned short f2bf(float x) {
    __hip_bfloat16 h = __float2bfloat16(x);           // RNE, hw cvt on gfx950
    union { __hip_bfloat16 h; unsigned short u; } v; v.h = h;
    return v.u;
}

// ---------------------------------------------------------------------------
// Kernel A: per (n, chunk-of-512-windows): layers 1+2, masked column sums.
// Wave w owns output channels [32w, 32w+32); all 64 rows of each step.
// ---------------------------------------------------------------------------
__global__ __launch_bounds__(256, 4) void pen_inner(
    const float* __restrict__ x,
    const float* __restrict__ w1, const float* __restrict__ b1,
    const float* __restrict__ w2, const float* __restrict__ b2,
    float* __restrict__ partials)
{
    // x windows as bf16, row stride 16 halfwords (32B): k0..8 = data, k9..15 = 0.
    // B-fragment for layer 1 is ONE aligned ds_read_b128 per lane: lanes lq>=1
    // read zeros / next-row data, which hit zeroed columns of A (k>=9) -> 0.
    __shared__ __align__(16) unsigned short xw[RPC * 16 + 64];
    // h1 tile, bf16 bits, XOR-swizzled halfword index within each 128-wide row.
    __shared__ __align__(16) unsigned short h1s[SR * HH];

    const int tid  = threadIdx.x;
    const int wave = tid >> 6;
    const int lane = tid & 63;
    const int lr   = lane & 15;   // MFMA "lane&15" index (A-row / B-col / D-col)
    const int lq   = lane >> 4;   // 0..3

    const int bx    = blockIdx.x;
    const int n     = bx >> 3;
    const int chunk = bx & 7;
    const int l0c   = chunk * RPC;

    const float* xn = x + n * (MM * TT);

    // ---- stage x windows as bf16 (once per block) ----
    #pragma unroll
    for (int k = 0; k < 8; ++k) {                 // k = i*3+m
        const int i = k / 3;
        const int m = k - i * 3;
        for (int r = tid; r < RPC; r += 256) {    // coalesced over t
            int t = l0c + r + i;
            float v = (t < TT) ? xn[m * TT + t] : 0.f;
            xw[r * 16 + k] = f2bf(v);
        }
    }
    for (int r = tid; r < RPC; r += 256) {        // k=8 plus zero pad k9..15
        int t = l0c + r + 2;
        float v = (t < TT) ? xn[2 * TT + t] : 0.f;
        u16x4 a; a[0] = f2bf(v); a[1] = 0; a[2] = 0; a[3] = 0;
        u16x4 z; z[0] = 0; z[1] = 0; z[2] = 0; z[3] = 0;
        *(u16x4*)&xw[r * 16 + 8]  = a;
        *(u16x4*)&xw[r * 16 + 12] = z;
    }
    if (tid < 64) xw[RPC * 16 + tid] = 0;         // tail pad (lq3 overread, r=511)

    // ---- preload weight fragments; biases go into the MFMA C operand ----
    const int fo0 = wave * 2;              // this wave's two 16-wide o-fragments
    bf16x8 w1f[2];                         // A1 = W1^T : [c][k], k>=9 zeroed
    bf16x8 w2f[2][4];                      // A2 = W2^T : [o][i], 4 k-chunks of 32
    f32x4  b1f[2], b2f[2];                 // bias in D-layout (row = lq*4+j)
    #pragma unroll
    for (int f = 0; f < 2; ++f) {
        const int c = (fo0 + f) * 16 + lr;
        bf16x8 a;
        #pragma unroll
        for (int e = 0; e < 8; ++e) {
            int k = lq * 8 + e;
            a[e] = (short)((k < 9) ? f2bf(w1[k * HH + c]) : (unsigned short)0);
        }
        w1f[f] = a;
        #pragma unroll
        for (int kk = 0; kk < 4; ++kk) {
            bf16x8 wv;
            #pragma unroll
            for (int e = 0; e < 8; ++e)
                wv[e] = (short)f2bf(w2[(kk * 32 + lq * 8 + e) * HH + c]);
            w2f[f][kk] = wv;
        }
        #pragma unroll
        for (int j = 0; j < 4; ++j) {
            b1f[f][j] = b1[(fo0 + f) * 16 + lq * 4 + j];
            b2f[f][j] = b2[(fo0 + f) * 16 + lq * 4 + j];
        }
    }

    float colsum[2][4] = {{0.f,0.f,0.f,0.f},{0.f,0.f,0.f,0.f}};

    for (int s = 0; s < STEPS; ++s) {
        __syncthreads();   // h1s reads of previous step complete (and xw staged, s==0)

        // ---- layer 1: D1[c][r] = W1^T @ xin^T + b1 (bias via C operand) ----
        f32x4 acc1[2][4];
        #pragma unroll
        for (int rf = 0; rf < 4; ++rf) {
            const int r = s * SR + rf * 16 + lr;                 // row within chunk
            bf16x8 bfrag = *(const bf16x8*)&xw[r * 16 + lq * 8]; // 16B aligned
            acc1[0][rf] = __builtin_amdgcn_mfma_f32_16x16x32_bf16(w1f[0], bfrag, b1f[0], 0, 0, 0);
            acc1[1][rf] = __builtin_amdgcn_mfma_f32_16x16x32_bf16(w1f[1], bfrag, b1f[1], 0, 0, 0);
        }

        // ---- relu + pack + swizzled LDS store: h1s[r][c], idx ^= (r&7)<<3 ----
        #pragma unroll
        for (int rf = 0; rf < 4; ++rf) {
            const int r   = rf * 16 + lr;
            const int swz = (r & 7) << 3;
            #pragma unroll
            for (int f = 0; f < 2; ++f) {
                const int cb = (fo0 + f) * 16 + lq * 4;
                unsigned p0 = f2bf(fmaxf(acc1[f][rf][0], 0.f));
                unsigned p1 = f2bf(fmaxf(acc1[f][rf][1], 0.f));
                unsigned p2 = f2bf(fmaxf(acc1[f][rf][2], 0.f));
                unsigned p3 = f2bf(fmaxf(acc1[f][rf][3], 0.f));
                u32x2 pk;
                pk[0] = p0 | (p1 << 16);
                pk[1] = p2 | (p3 << 16);
                *(u32x2*)&h1s[r * HH + (cb ^ swz)] = pk;
            }
        }
        __syncthreads();

        // ---- layer 2: D2[o][r] = W2^T @ h1^T + b2, 4 K-chunks ----
        f32x4 acc2[2][4];
        #pragma unroll
        for (int rf = 0; rf < 4; ++rf) {
            const int r   = rf * 16 + lr;
            const int swz = (r & 7) << 3;
            bf16x8 hf[4];
            #pragma unroll
            for (int kk = 0; kk < 4; ++kk)
                hf[kk] = *(const bf16x8*)&h1s[r * HH + ((kk * 32 + lq * 8) ^ swz)];
            acc2[0][rf] = __builtin_amdgcn_mfma_f32_16x16x32_bf16(w2f[0][0], hf[0], b2f[0], 0, 0, 0);
            acc2[1][rf] = __builtin_amdgcn_mfma_f32_16x16x32_bf16(w2f[1][0], hf[0], b2f[1], 0, 0, 0);
            #pragma unroll
            for (int kk = 1; kk < 4; ++kk) {
                acc2[0][rf] = __builtin_amdgcn_mfma_f32_16x16x32_bf16(w2f[0][kk], hf[kk], acc2[0][rf], 0, 0, 0);
                acc2[1][rf] = __builtin_amdgcn_mfma_f32_16x16x32_bf16(w2f[1][kk], hf[kk], acc2[1][rf], 0, 0, 0);
            }
        }

        // ---- relu + column-sum; tail mask only on the one affected rf ----
        const bool tailstep = (chunk == CHUNKS - 1) && (s == STEPS - 1);
        #pragma unroll
        for (int rf = 0; rf < 4; ++rf) {
            if (tailstep && rf == 3) {                  // rows 4080+lr; valid iff lr<14
                const bool valid = lr < 14;
                #pragma unroll
                for (int f = 0; f < 2; ++f)
                    #pragma unroll
                    for (int j = 0; j < 4; ++j) {
                        float v = fmaxf(acc2[f][rf][j], 0.f);
                        if (valid) colsum[f][j] += v;
                    }
            } else {
                #pragma unroll
                for (int f = 0; f < 2; ++f)
                    #pragma unroll
                    for (int j = 0; j < 4; ++j)
                        colsum[f][j] += fmaxf(acc2[f][rf][j], 0.f);
            }
        }
    }

    // ---- reduce colsum over the 16 r-lanes, write block partial (no atomics) ----
    #pragma unroll
    for (int f = 0; f < 2; ++f)
        #pragma unroll
        for (int j = 0; j < 4; ++j) {
            float v = colsum[f][j];
            #pragma unroll
            for (int msk = 1; msk < 16; msk <<= 1)
                v += __shfl_xor(v, msk, 64);
            if (lr == 0) {
                const int o = (fo0 + f) * 16 + lq * 4 + j;
                partials[(n * CHUNKS + chunk) * HH + o] = v;
            }
        }
}

// ---------------------------------------------------------------------------
// Kernel B: tail in fp32. inner = sum partials; oi = inner@W3 + L*b3;
// io = [x[:, :, :2] flat (6), oi]; g = relu(io@rw1+rb1); out = g@rw2+rb2.
// ---------------------------------------------------------------------------
__global__ __launch_bounds__(128) void pen_outer(
    const float* __restrict__ x,
    const float* __restrict__ w3, const float* __restrict__ b3,
    const float* __restrict__ rw1, const float* __restrict__ rb1,
    const float* __restrict__ rw2, const float* __restrict__ rb2,
    const float* __restrict__ partials,
    float* __restrict__ out)
{
    __shared__ float S[HH];
    __shared__ float IO[136];
    __shared__ float G[HH];
    const int n = blockIdx.x;
    const int c = threadIdx.x;

    float s = 0.f;
    #pragma unroll
    for (int ch = 0; ch < CHUNKS; ++ch)
        s += partials[(n * CHUNKS + ch) * HH + c];
    S[c] = s;
    if (c < 6) IO[c] = x[n * (MM * TT) + (c >> 1) * TT + (c & 1)];
    __syncthreads();

    float oi = (float)LL * b3[c];
    for (int k = 0; k < HH; ++k) oi += S[k] * w3[k * HH + c];
    IO[6 + c] = oi;
    __syncthreads();

    float g = rb1[c];
    for (int k = 0; k < 134; ++k) g += IO[k] * rw1[k * HH + c];
    G[c] = fmaxf(g, 0.f);
    __syncthreads();

    if (c < 10) {
        float o = rb2[c];
        for (int k = 0; k < HH; ++k) o += G[k] * rw2[k * 10 + c];
        out[n * 10 + c] = o;
    }
}

// ---------------------------------------------------------------------------
extern "C" void kernel_launch(void* const* d_in, const int* in_sizes, int n_in,
                              void* d_out, int out_size, void* d_ws, size_t ws_size,
                              hipStream_t stream)
{
    (void)in_sizes; (void)n_in; (void)out_size; (void)ws_size;
    const float* x   = (const float*)d_in[0];
    const float* w1  = (const float*)d_in[1];
    const float* b1  = (const float*)d_in[2];
    const float* w2  = (const float*)d_in[3];
    const float* b2  = (const float*)d_in[4];
    const float* w3  = (const float*)d_in[5];
    const float* b3  = (const float*)d_in[6];
    const float* rw1 = (const float*)d_in[7];
    const float* rb1 = (const float*)d_in[8];
    const float* rw2 = (const float*)d_in[9];
    const float* rb2 = (const float*)d_in[10];

    float* partials = (float*)d_ws;   // NN*CHUNKS*HH floats = 1 MiB of scratch

    pen_inner<<<NN * CHUNKS, 256, 0, stream>>>(x, w1, b1, w2, b2, partials);
    pen_outer<<<NN, 128, 0, stream>>>(x, w3, b3, rw1, rb1, rw2, rb2, partials,
                                      (float*)d_out);
}